// Round 8
// baseline (99.502 us; speedup 1.0000x reference)
//
#include <hip/hip_runtime.h>
#include <hip/hip_bf16.h>
#include <stdint.h>

#define NDEC 8192
#define NENC 8192
#define IND  512
#define OUTD 64

typedef __attribute__((ext_vector_type(8))) short bf16x8;
typedef __attribute__((ext_vector_type(4))) float f32x4;
typedef __attribute__((ext_vector_type(16))) float f32x16;

static __device__ __forceinline__ uint32_t pkbf(float a, float b) {
    union { __hip_bfloat162 h; uint32_t u; } c;
    c.h = __float22bfloat162_rn(make_float2(a, b));   // v_cvt_pk_bf16_f32
    return c.u;
}
static __device__ __forceinline__ unsigned short f2bfu(float f) {
    union { __hip_bfloat16 h; unsigned short u; } c;
    c.h = __float2bfloat16(f);
    return c.u;
}
static __device__ __forceinline__ bf16x8 cvt8(float4 a, float4 b) {
    union { uint32_t u[4]; bf16x8 v; } r;
    r.u[0] = pkbf(a.x, a.y); r.u[1] = pkbf(a.z, a.w);
    r.u[2] = pkbf(b.x, b.y); r.u[3] = pkbf(b.z, b.w);
    return r.v;
}
// sigma: involutive permutation on bits[3:2] (01 <-> 10), identity elsewhere.
static __device__ __forceinline__ int sig4(int u) {
    return (u & ~12) | ((u & 4) << 1) | ((u & 8) >> 1);
}
// LDS tile swizzle: (row, c) -> byte offset; c in 16B units, 8 per 128B row.
static __device__ __forceinline__ int swz(int row, int c) {
    return (row << 7) + ((c ^ (row & 7)) << 4);
}

// ---------------------------------------------------------------------------
// Stage 0: prep — W[512][64] f32 x3 -> WTb[mat][n=64][k=512] bf16 in global.
// Softmax/scale constant folded into Wq. 192 KB total, L2-resident afterwards.
// ---------------------------------------------------------------------------
__global__ __launch_bounds__(256) void prep_kernel(
    const float* __restrict__ wq, const float* __restrict__ wk, const float* __restrict__ wv,
    unsigned short* __restrict__ WTb)
{
    int idx = blockIdx.x * 256 + threadIdx.x;   // 0 .. 3*32768-1
    int mat = idx >> 15;
    int r = idx & 32767;                        // k*64 + n
    int k = r >> 6, n = r & 63;
    const float* W = (mat == 0) ? wq : ((mat == 1) ? wk : wv);
    float s = (mat == 0) ? 0.18033688011112042f : 1.0f;  // 0.125*log2(e)
    WTb[mat * 32768 + n * 512 + k] = f2bfu(W[r] * s);
}

// ---------------------------------------------------------------------------
// Stage 1: projections (no LDS, no barrier — WT fragments read from L2).
//   mat 0: q = x@(Wq*c) -> qbuf[8192][64] bf16
//   mat 1: k = E@Wk     -> kbuf[8192][64] bf16
//   mat 2: vTt = (E@Wv)^T tiled [tok/64][64 f][64 tok], sigma-permuted
// ---------------------------------------------------------------------------
__global__ __launch_bounds__(256) void proj_kernel(
    const float* __restrict__ x, const float* __restrict__ emb,
    const unsigned short* __restrict__ WTb,
    unsigned short* __restrict__ qbuf, unsigned short* __restrict__ kbuf,
    unsigned short* __restrict__ vTt)
{
    const int mat = blockIdx.y;
    const unsigned short* WT = WTb + mat * 32768;
    const int t = threadIdx.x;
    const int wave = t >> 6, lane = t & 63;
    const int lo = lane & 15, g = lane >> 4;

    f32x4 acc[4];
    #pragma unroll
    for (int nf = 0; nf < 4; ++nf) acc[nf] = (f32x4){0.f, 0.f, 0.f, 0.f};

    if (mat < 2) {
        const float* A = (mat == 0) ? x : emb;
        const int rbase = blockIdx.x * 64 + wave * 16;
        const float* arow = A + (size_t)(rbase + lo) * IND + g * 8;
        // prefetch A and WT fragments one iteration ahead
        float4 a0 = *(const float4*)(arow);
        float4 a1 = *(const float4*)(arow + 4);
        bf16x8 wf[4];
        #pragma unroll
        for (int nf = 0; nf < 4; ++nf)
            wf[nf] = *(const bf16x8*)(WT + (nf * 16 + lo) * 512 + g * 8);
        #pragma unroll
        for (int ks = 0; ks < 16; ++ks) {
            float4 n0 = a0, n1 = a1;
            bf16x8 wn[4] = {wf[0], wf[1], wf[2], wf[3]};
            if (ks < 15) {
                n0 = *(const float4*)(arow + (ks + 1) * 32);
                n1 = *(const float4*)(arow + (ks + 1) * 32 + 4);
                #pragma unroll
                for (int nf = 0; nf < 4; ++nf)
                    wn[nf] = *(const bf16x8*)(WT + (nf * 16 + lo) * 512 + (ks + 1) * 32 + g * 8);
            }
            bf16x8 af = cvt8(a0, a1);
            #pragma unroll
            for (int nf = 0; nf < 4; ++nf)
                acc[nf] = __builtin_amdgcn_mfma_f32_16x16x32_bf16(af, wf[nf], acc[nf], 0, 0, 0);
            a0 = n0; a1 = n1;
            #pragma unroll
            for (int nf = 0; nf < 4; ++nf) wf[nf] = wn[nf];
        }
        unsigned short* obuf = (mat == 0) ? qbuf : kbuf;
        #pragma unroll
        for (int nf = 0; nf < 4; ++nf)
            #pragma unroll
            for (int r = 0; r < 4; ++r)
                obuf[(size_t)(rbase + 4 * g + r) * OUTD + nf * 16 + lo] = f2bfu(acc[nf][r]);
    } else {
        const int f = wave * 16 + lo;
        const int tbase = blockIdx.x * 64;
        #pragma unroll 2
        for (int ks = 0; ks < 16; ++ks) {
            int k0 = ks * 32 + g * 8;
            bf16x8 wf = *(const bf16x8*)(WT + f * 512 + k0);
            #pragma unroll
            for (int nf = 0; nf < 4; ++nf) {
                const float* erow = emb + (size_t)(tbase + nf * 16 + lo) * IND + k0;
                float4 e0 = *(const float4*)(erow);
                float4 e1 = *(const float4*)(erow + 4);
                bf16x8 ef = cvt8(e0, e1);
                acc[nf] = __builtin_amdgcn_mfma_f32_16x16x32_bf16(wf, ef, acc[nf], 0, 0, 0);
            }
        }
        const int lop = sig4(lo);
        unsigned short* vblk = vTt + (size_t)(tbase >> 6) * 4096;
        #pragma unroll
        for (int nf = 0; nf < 4; ++nf)
            #pragma unroll
            for (int r = 0; r < 4; ++r)
                vblk[(wave * 16 + 4 * g + r) * 64 + nf * 16 + lop] = f2bfu(acc[nf][r]);
    }
}

// ---------------------------------------------------------------------------
// Stage 2: flash attention. 32x32x16 MFMA, swapped QK^T / swapped PV, sigma-
// permuted PV K-axis, fixed softmax shift (C-init -16), ones-MFMA row-sum.
// Mega-tiling: stage 256 tokens (K 32KB + V 32KB LDS, XOR swizzle) once, then
// 4 inner sub-tiles compute LDS-only (no barriers, no global). T14 early
// issue of the next mega's loads. 3 barriers per block total (nmega=2).
// Grid (NDEC/128, nsplit). Partials: O bf16, l f32 (shared exp2 offset).
// ---------------------------------------------------------------------------
__global__ __launch_bounds__(256) void attn_kernel(
    const unsigned short* __restrict__ qbuf, const unsigned short* __restrict__ kbuf,
    const unsigned short* __restrict__ vTt,
    unsigned short* __restrict__ Opart, float* __restrict__ Lpart,
    int chunk)
{
    __shared__ char lds[65536];   // K: [0,32K) swz rows 0-255; V: 32K + sub*8K + swz
    const int t = threadIdx.x;
    const int wave = t >> 6, lane = t & 63;
    const int r32 = lane & 31, hi = lane >> 5;
    const int qrow = blockIdx.x * 128 + wave * 32 + r32;
    const int split = blockIdx.y;
    const int tok0 = split * chunk;
    const int nmega = chunk >> 8;

    bf16x8 qf[4];
    #pragma unroll
    for (int kt = 0; kt < 4; ++kt)
        qf[kt] = *(const bf16x8*)(qbuf + (size_t)qrow * OUTD + kt * 16 + hi * 8);

    union { uint32_t u[4]; bf16x8 v; } ones;
    #pragma unroll
    for (int j = 0; j < 4; ++j) ones.u[j] = 0x3F803F80u;   // bf16 1.0 pair

    f32x16 o0 = (f32x16)(0.f), o1 = (f32x16)(0.f), lacc = (f32x16)(0.f);

    uint4 stK[8], stV[8];
    auto LOADS = [&](int tb) {
        const uint4* kb4 = (const uint4*)(kbuf + (size_t)tb * 64);
        const uint4* vb4 = (const uint4*)(vTt + (size_t)tb * 64);
        #pragma unroll
        for (int r8 = 0; r8 < 8; ++r8) {
            stK[r8] = kb4[r8 * 256 + t];
            stV[r8] = vb4[r8 * 256 + t];
        }
    };
    auto WRITES = [&]() {
        #pragma unroll
        for (int r8 = 0; r8 < 8; ++r8) {
            int j = r8 * 256 + t;
            int row = j >> 3, c = j & 7;
            *(uint4*)(lds + swz(row, c)) = stK[r8];
            int sub = j >> 9, f = (j >> 3) & 63;
            *(uint4*)(lds + 32768 + sub * 8192 + swz(f, c)) = stV[r8];
        }
    };

    LOADS(tok0);
    WRITES();
    __syncthreads();

    for (int mi = 0; mi < nmega; ++mi) {
        if (mi + 1 < nmega) LOADS(tok0 + (mi + 1) * 256);   // early issue (T14)

        #pragma unroll
        for (int it4 = 0; it4 < 4; ++it4) {
            const char* kb = lds;
            const char* vb = lds + 32768 + it4 * 8192;
            const int trow = it4 * 64;

            bf16x8 kA[4], kB[4];
            #pragma unroll
            for (int kt = 0; kt < 4; ++kt) {
                const int c = kt * 2 + hi;
                kA[kt] = *(const bf16x8*)(kb + swz(trow + r32, c));
                kB[kt] = *(const bf16x8*)(kb + swz(trow + 32 + r32, c));
            }

            f32x16 sA = (f32x16)(-16.f), sB = (f32x16)(-16.f);
            __builtin_amdgcn_s_setprio(1);
            #pragma unroll
            for (int kt = 0; kt < 4; ++kt) {
                sA = __builtin_amdgcn_mfma_f32_32x32x16_bf16(kA[kt], qf[kt], sA, 0, 0, 0);
                sB = __builtin_amdgcn_mfma_f32_32x32x16_bf16(kB[kt], qf[kt], sB, 0, 0, 0);
            }
            __builtin_amdgcn_s_setprio(0);

            #pragma unroll
            for (int r = 0; r < 16; ++r) {
                sA[r] = __builtin_amdgcn_exp2f(sA[r]);
                sB[r] = __builtin_amdgcn_exp2f(sB[r]);
            }

            union { uint32_t u[4]; bf16x8 v; } pA0, pA1, pB0, pB1;
            #pragma unroll
            for (int j = 0; j < 4; ++j) {
                pA0.u[j] = pkbf(sA[2 * j], sA[2 * j + 1]);
                pA1.u[j] = pkbf(sA[8 + 2 * j], sA[9 + 2 * j]);
                pB0.u[j] = pkbf(sB[2 * j], sB[2 * j + 1]);
                pB1.u[j] = pkbf(sB[8 + 2 * j], sB[9 + 2 * j]);
            }

            bf16x8 vA[4], vB[4];
            #pragma unroll
            for (int ft = 0; ft < 2; ++ft)
                #pragma unroll
                for (int kt = 0; kt < 2; ++kt) {
                    const int row = ft * 32 + r32;
                    vA[ft * 2 + kt] = *(const bf16x8*)(vb + swz(row, kt * 2 + hi));
                    vB[ft * 2 + kt] = *(const bf16x8*)(vb + swz(row, 4 + kt * 2 + hi));
                }

            __builtin_amdgcn_s_setprio(1);
            lacc = __builtin_amdgcn_mfma_f32_32x32x16_bf16(ones.v, pA0.v, lacc, 0, 0, 0);
            lacc = __builtin_amdgcn_mfma_f32_32x32x16_bf16(ones.v, pA1.v, lacc, 0, 0, 0);
            lacc = __builtin_amdgcn_mfma_f32_32x32x16_bf16(ones.v, pB0.v, lacc, 0, 0, 0);
            lacc = __builtin_amdgcn_mfma_f32_32x32x16_bf16(ones.v, pB1.v, lacc, 0, 0, 0);
            o0 = __builtin_amdgcn_mfma_f32_32x32x16_bf16(vA[0], pA0.v, o0, 0, 0, 0);
            o1 = __builtin_amdgcn_mfma_f32_32x32x16_bf16(vA[2], pA0.v, o1, 0, 0, 0);
            o0 = __builtin_amdgcn_mfma_f32_32x32x16_bf16(vA[1], pA1.v, o0, 0, 0, 0);
            o1 = __builtin_amdgcn_mfma_f32_32x32x16_bf16(vA[3], pA1.v, o1, 0, 0, 0);
            o0 = __builtin_amdgcn_mfma_f32_32x32x16_bf16(vB[0], pB0.v, o0, 0, 0, 0);
            o1 = __builtin_amdgcn_mfma_f32_32x32x16_bf16(vB[2], pB0.v, o1, 0, 0, 0);
            o0 = __builtin_amdgcn_mfma_f32_32x32x16_bf16(vB[1], pB1.v, o0, 0, 0, 0);
            o1 = __builtin_amdgcn_mfma_f32_32x32x16_bf16(vB[3], pB1.v, o1, 0, 0, 0);
            __builtin_amdgcn_s_setprio(0);
        }

        if (mi + 1 < nmega) {
            __syncthreads();   // all reads of this mega done
            WRITES();
            __syncthreads();   // next mega staged
        }
    }

    // finalize: every lane's lacc[0] is its q-row's full Σp
    if (hi == 0)
        Lpart[(size_t)split * NDEC + qrow] = lacc[0];
    unsigned short* orow = Opart + ((size_t)split * NDEC + qrow) * OUTD;
    #pragma unroll
    for (int q = 0; q < 4; ++q) {
        uint2 st0, st1;
        st0.x = pkbf(o0[q * 4 + 0], o0[q * 4 + 1]);
        st0.y = pkbf(o0[q * 4 + 2], o0[q * 4 + 3]);
        st1.x = pkbf(o1[q * 4 + 0], o1[q * 4 + 1]);
        st1.y = pkbf(o1[q * 4 + 2], o1[q * 4 + 3]);
        *(uint2*)(orow + q * 8 + hi * 4) = st0;
        *(uint2*)(orow + 32 + q * 8 + hi * 4) = st1;
    }
}

// ---------------------------------------------------------------------------
// Stage 3: combine splits (shared exp2 offset -> plain sums) and normalize.
// ---------------------------------------------------------------------------
__global__ __launch_bounds__(256) void combine_kernel(
    const unsigned short* __restrict__ Opart, const float* __restrict__ Lpart,
    float* __restrict__ out, int nsplit)
{
    int idx = blockIdx.x * 256 + threadIdx.x;   // row*8 + f8
    int row = idx >> 3;
    int fo = (idx & 7) * 8;
    float L = 0.f;
    float acc[8];
    #pragma unroll
    for (int j = 0; j < 8; ++j) acc[j] = 0.f;
    for (int s = 0; s < nsplit; ++s) {
        L += Lpart[(size_t)s * NDEC + row];
        uint4 v = *(const uint4*)(Opart + ((size_t)s * NDEC + row) * OUTD + fo);
        uint32_t u[4] = {v.x, v.y, v.z, v.w};
        #pragma unroll
        for (int j = 0; j < 4; ++j) {
            union { uint32_t u; float f; } lo2, hi2;
            lo2.u = u[j] << 16;
            hi2.u = u[j] & 0xFFFF0000u;
            acc[2 * j]     += lo2.f;
            acc[2 * j + 1] += hi2.f;
        }
    }
    float inv = 1.f / L;
    float4 s0, s1;
    s0.x = acc[0] * inv; s0.y = acc[1] * inv; s0.z = acc[2] * inv; s0.w = acc[3] * inv;
    s1.x = acc[4] * inv; s1.y = acc[5] * inv; s1.z = acc[6] * inv; s1.w = acc[7] * inv;
    *(float4*)(out + (size_t)row * OUTD + fo) = s0;
    *(float4*)(out + (size_t)row * OUTD + fo + 4) = s1;
}

extern "C" void kernel_launch(void* const* d_in, const int* in_sizes, int n_in,
                              void* d_out, int out_size, void* d_ws, size_t ws_size,
                              hipStream_t stream) {
    const float* x   = (const float*)d_in[0];
    const float* emb = (const float*)d_in[1];
    const float* wq  = (const float*)d_in[2];
    const float* wk  = (const float*)d_in[3];
    const float* wv  = (const float*)d_in[4];
    float* out = (float*)d_out;
    char* ws = (char*)d_ws;

    unsigned short* qbuf = (unsigned short*)ws;                  // 1 MiB
    unsigned short* kbuf = (unsigned short*)(ws + (1u << 20));   // 1 MiB
    unsigned short* vTt  = (unsigned short*)(ws + (2u << 20));   // 1 MiB
    unsigned short* WTb  = (unsigned short*)(ws + (3u << 20));   // 192 KiB
    const size_t obase = (3u << 20) + (1u << 18);
    const size_t per_split = (size_t)NDEC * OUTD * 2 + (size_t)NDEC * 4;  // O bf16 + l f32
    int nsplit = 16;
    while (nsplit > 4 && obase + (size_t)nsplit * per_split > ws_size) nsplit >>= 1;
    unsigned short* Opart = (unsigned short*)(ws + obase);
    float* Lpart = (float*)(ws + obase + (size_t)nsplit * NDEC * OUTD * 2);

    hipLaunchKernelGGL(prep_kernel, dim3(384), dim3(256), 0, stream,
                       wq, wk, wv, WTb);
    hipLaunchKernelGGL(proj_kernel, dim3(NDEC / 64, 3), dim3(256), 0, stream,
                       x, emb, WTb, qbuf, kbuf, vTt);
    hipLaunchKernelGGL(attn_kernel, dim3(NDEC / 128, nsplit), dim3(256), 0, stream,
                       qbuf, kbuf, vTt, Opart, Lpart, NENC / nsplit);
    hipLaunchKernelGGL(combine_kernel, dim3((NDEC * 8) / 256), dim3(256), 0, stream,
                       Opart, Lpart, out, nsplit);
}